// Round 9
// baseline (200.557 us; speedup 1.0000x reference)
//
#include <hip/hip_runtime.h>
#include <stdint.h>

#define B_   4
#define S_   2048
#define E_   1024
#define MQKV (B_ * S_)
#define LDP  2112   // padded row stride (u16) for Pm and vt

typedef __bf16 bf16x8 __attribute__((ext_vector_type(8)));
typedef float f32x4 __attribute__((ext_vector_type(4)));
typedef unsigned short u16;
typedef unsigned int u32;

__device__ __forceinline__ u16 f2bf(float x) {
  union { float f; u32 u; } c; c.f = x;
  u32 r = (c.u + 0x7FFFu + ((c.u >> 16) & 1u)) >> 16;
  return (u16)r;
}
__device__ __forceinline__ float bf2f(u16 h) {
  union { u32 u; float f; } c; c.u = ((u32)h) << 16;
  return c.f;
}

__global__ __launch_bounds__(256) void cvt_f32_bf16(const float* __restrict__ src,
                                                    u16* __restrict__ dst, int n4) {
  int i = blockIdx.x * blockDim.x + threadIdx.x;
  int st = gridDim.x * blockDim.x;
  for (; i < n4; i += st) {
    float4 f = reinterpret_cast<const float4*>(src)[i];
    ushort4 o;
    o.x = f2bf(f.x); o.y = f2bf(f.y); o.z = f2bf(f.z); o.w = f2bf(f.w);
    reinterpret_cast<ushort4*>(dst)[i] = o;
  }
}

__global__ __launch_bounds__(256) void cvt_w3(const float* __restrict__ wq,
                                              const float* __restrict__ wk,
                                              const float* __restrict__ wv,
                                              u16* __restrict__ dst) {
  const int per = E_ * E_ / 4;
  int i = blockIdx.x * blockDim.x + threadIdx.x;
  const int sel = i / per;
  const int r = i - sel * per;
  const float* src = sel == 0 ? wq : (sel == 1 ? wk : wv);
  float4 f = reinterpret_cast<const float4*>(src)[r];
  ushort4 o;
  o.x = f2bf(f.x); o.y = f2bf(f.y); o.z = f2bf(f.z); o.w = f2bf(f.w);
  reinterpret_cast<ushort4*>(dst)[i] = o;
}

#define GLOAD_LDS16(g, l)                                                      \
  __builtin_amdgcn_global_load_lds(                                            \
      (const __attribute__((address_space(1))) u32*)(g),                       \
      (__attribute__((address_space(3))) u32*)(l), 16, 0, 0)

// ============================================================================
// 256-row-tile GEMM (ring), 8 waves (2M x 4N), BK=32, 4-slot LDS ring,
// counted vmcnt, 2-way-free XOR swizzle (chunk ^= (row>>1)&3), setprio,
// XCD swizzle. C = A(M x K, ldA) * Bt(N x K, ldB)^T, bf16 in, f32 acc.
// EPI 0: qk-projection: +bias, scatter col<1024 -> q, else -> k
// EPI 1: v-projection-transposed: +b0[row], bf16, ldC-strided (z-batched)
// EPI 2: exp(v*scale), bf16, ldC-strided
// EPI 4: unsafeAtomicAdd(out, v * invL[row])  (split-K PV; out pre-zeroed)
// KS: 1 = split-K=2 decode (id>=nwg/2 -> second K half)
// ============================================================================
template <int BN, int EPI, int KS>
__global__ __launch_bounds__(512, 2) void gemm256(
    const u16* __restrict__ A, const u16* __restrict__ Bt, void* __restrict__ Cv,
    const float* __restrict__ b0, const float* __restrict__ b1,
    int N, int K, float scale,
    long sA, long sB, long sC, long ldA, long ldB, long ldC, int gx, int gy) {
  constexpr int BM = 256;
  constexpr int NR = BN / 64;
  constexpr int L  = 2 + BN / 128;
  constexpr int BSLOT = BN * 32;

  __shared__ alignas(16) u16 lds[4 * BM * 32 + 4 * BSLOT];
  u16* lA = lds;
  u16* lB = lds + 4 * BM * 32;

  const int t = threadIdx.x;
  const int wv = t >> 6;
  const int ln = t & 63;
  const int wm = wv >> 2;
  const int wn = wv & 3;

  const int nwg = gridDim.x;
  int id = blockIdx.x;
  id = (id & 7) * (nwg >> 3) + (id >> 3);
  int ks = 0;
  if constexpr (KS) {
    const int half = nwg >> 1;
    ks = id >= half;
    id -= ks * half;
  }
  const int pz = gx * gy;
  const int z = id / pz;
  const int r2 = id - z * pz;
  const int by = r2 / gx;
  const int bx = r2 - by * gx;
  const int bm = by * BM;
  const int bn = bx * BN;

  A += (size_t)z * sA + (size_t)ks * K;
  Bt += (size_t)z * sB + (size_t)ks * K;

  const int srow = t >> 2;
  const int g0 = (t & 3) ^ ((srow >> 1) & 3);       // 2-way-free swizzle
  const u16* gA0 = A + (size_t)(bm + srow) * ldA + g0 * 8;
  const u16* gA1 = gA0 + (size_t)128 * ldA;
  const u16* gB0 = Bt + (size_t)(bn + srow) * ldB + g0 * 8;
  const u16* gB1 = gB0 + (size_t)128 * ldB;

  auto STAGE = [&](int u) {
    const int s = u & 3;
    const int ko = u * 32;
    GLOAD_LDS16(gA0 + ko, lA + s * 8192 + wv * 512);
    GLOAD_LDS16(gA1 + ko, lA + s * 8192 + 4096 + wv * 512);
    GLOAD_LDS16(gB0 + ko, lB + s * BSLOT + wv * 512);
    if constexpr (BN == 256) GLOAD_LDS16(gB1 + ko, lB + s * BSLOT + 4096 + wv * 512);
  };

  const int lrow = ln & 15;
  const int g = ln >> 4;
  const int aR = wm * 128 + lrow;
  const int aOff = aR * 32 + (g ^ ((aR >> 1) & 3)) * 8;
  const int bR = wn * (BN / 4) + lrow;
  const int bOff = bR * 32 + (g ^ ((bR >> 1) & 3)) * 8;

  f32x4 acc[8][NR] = {};
  const int T = K >> 5;

  bf16x8 afA[8], afB[8], bgA[NR], bgB[NR];

#define RD_A(DST, TILE) do { const u16* _p = lA + ((TILE) & 3) * 8192 + aOff;  \
  _Pragma("unroll") for (int _i = 0; _i < 8; ++_i)                             \
    DST[_i] = *reinterpret_cast<const bf16x8*>(_p + _i * 512); } while (0)
#define RD_B(DST, TILE) do { const u16* _p = lB + ((TILE) & 3) * BSLOT + bOff; \
  _Pragma("unroll") for (int _j = 0; _j < NR; ++_j)                            \
    DST[_j] = *reinterpret_cast<const bf16x8*>(_p + _j * 512); } while (0)
#define DO_MFMA(AF, BG) do { __builtin_amdgcn_s_setprio(1);                    \
  _Pragma("unroll") for (int _i = 0; _i < 8; ++_i)                             \
  _Pragma("unroll") for (int _j = 0; _j < NR; ++_j)                            \
    acc[_i][_j] = __builtin_amdgcn_mfma_f32_16x16x32_bf16(AF[_i], BG[_j],      \
                                                          acc[_i][_j], 0, 0, 0);\
  __builtin_amdgcn_s_setprio(0); } while (0)
#define VM_GATE(COND) do {                                                     \
  if (COND) { asm volatile("s_waitcnt vmcnt(%0)" :: "n"(L) : "memory"); }      \
  else { asm volatile("s_waitcnt vmcnt(0)" ::: "memory"); }                    \
  __builtin_amdgcn_s_barrier(); asm volatile("" ::: "memory"); } while (0)

  STAGE(0); STAGE(1); STAGE(2);
  asm volatile("s_waitcnt vmcnt(%0)" :: "n"(L) : "memory");
  __builtin_amdgcn_s_barrier();
  asm volatile("" ::: "memory");

  if constexpr (NR == 2) { RD_A(afA, 0); RD_B(bgA, 0); }
  else                   { RD_B(bgA, 0); }

  for (int tt = 0; tt < T; tt += 2) {
    if (tt + 3 < T) STAGE(tt + 3);
    if constexpr (NR == 2) { RD_A(afB, tt + 1); RD_B(bgB, tt + 1); DO_MFMA(afA, bgA); }
    else                   { RD_A(afA, tt); RD_B(bgB, tt + 1);     DO_MFMA(afA, bgA); }
    VM_GATE(tt + 3 < T);

    if (tt + 4 < T) STAGE(tt + 4);
    if constexpr (NR == 2) {
      if (tt + 2 < T) { RD_A(afA, tt + 2); RD_B(bgA, tt + 2); }
      DO_MFMA(afB, bgB);
    } else {
      RD_A(afA, tt + 1);
      if (tt + 2 < T) RD_B(bgA, tt + 2);
      DO_MFMA(afA, bgB);
    }
    VM_GATE(tt + 4 < T);
  }
#undef RD_A
#undef RD_B
#undef DO_MFMA
#undef VM_GATE

  const int r0 = (ln >> 4) * 4;
  const int c0 = ln & 15;
#pragma unroll
  for (int i = 0; i < 8; ++i) {
#pragma unroll
    for (int j = 0; j < NR; ++j) {
      const int col = bn + wn * (BN / 4) + j * 16 + c0;
#pragma unroll
      for (int ii = 0; ii < 4; ++ii) {
        const int row = bm + wm * 128 + i * 16 + r0 + ii;
        float v = acc[i][j][ii];
        if constexpr (EPI == 0) {
          const int sel = col >> 10;
          const int cc = col & 1023;
          const float bb = sel == 0 ? b0[cc] : b1[cc];
          ((u16*)Cv)[(size_t)sel * 8388608 + (size_t)row * 1024 + cc] = f2bf(v + bb);
        } else if constexpr (EPI == 1) {
          ((u16*)Cv)[(size_t)z * sC + (size_t)row * ldC + col] = f2bf(v + b0[row]);
        } else if constexpr (EPI == 2) {
          ((u16*)Cv)[(size_t)z * sC + (size_t)row * ldC + col] = f2bf(__expf(v * scale));
        } else {
          const float sc = b0[z * 2048 + row];
          unsafeAtomicAdd(&((float*)Cv)[(size_t)z * sC + (size_t)row * ldC + col],
                          v * sc);
        }
      }
    }
  }
}

// invL[row] = 1 / sum(expS[row][:2048]) ; one wave per row; Pm rows LDP-strided
__global__ __launch_bounds__(256) void row_invsum(const u16* __restrict__ P,
                                                  float* __restrict__ invL) {
  const int row = blockIdx.x * 4 + (threadIdx.x >> 6);
  const int ln = threadIdx.x & 63;
  const u16* p = P + (size_t)row * LDP + ln * 32;
  float s = 0.f;
#pragma unroll
  for (int q = 0; q < 4; ++q) {
    uint4 r = reinterpret_cast<const uint4*>(p)[q];
    u32 w[4] = {r.x, r.y, r.z, r.w};
#pragma unroll
    for (int k = 0; k < 4; ++k) {
      s += bf2f((u16)(w[k] & 0xffffu));
      s += bf2f((u16)(w[k] >> 16));
    }
  }
  for (int o = 1; o < 64; o <<= 1) s += __shfl_xor(s, o);
  if (ln == 0) invL[row] = 1.0f / s;
}

extern "C" void kernel_launch(void* const* d_in, const int* in_sizes, int n_in,
                              void* d_out, int out_size, void* d_ws, size_t ws_size,
                              hipStream_t stream) {
  const float* x = (const float*)d_in[0];
  const float* Wq = (const float*)d_in[1];
  const float* bq = (const float*)d_in[2];
  const float* Wk = (const float*)d_in[3];
  const float* bk = (const float*)d_in[4];
  const float* Wv = (const float*)d_in[5];
  const float* bv = (const float*)d_in[6];
  float* out = (float*)d_out;

  const size_t xE = 8388608, wE = 3145728, qE = 8388608;
  const size_t vtE = (size_t)4 * 1024 * LDP;
  const size_t PmE = (size_t)4 * 2048 * LDP;
  const size_t need = (xE + wE + 2 * qE + vtE + PmE) * 2 + (size_t)MQKV * 4;
  if (ws_size < need) {
    hipMemsetAsync(d_out, 0, (size_t)out_size * sizeof(float), stream);
    return;
  }
  u16* xb = (u16*)d_ws;
  u16* wqkv = xb + xE;
  u16* qb = wqkv + wE;            // k at qb + 8388608 (EPI0 hardcodes the offset)
  u16* vt = qb + 2 * qE;
  u16* Pm = vt + vtE;
  float* invL = (float*)(Pm + PmE);

  // 1) fp32 -> bf16
  cvt_f32_bf16<<<2048, 256, 0, stream>>>(x, xb, MQKV * E_ / 4);
  cvt_w3<<<3 * E_ * E_ / 4 / 256, 256, 0, stream>>>(Wq, Wk, Wv, wqkv);

  // zero the output (PV accumulates atomically)
  hipMemsetAsync(out, 0, (size_t)MQKV * E_ * sizeof(float), stream);

  // 2) qk-projection: [8192,1024] x [2048,1024]^T -> q | k (256 blocks)
  gemm256<256, 0, 0><<<256, 512, 0, stream>>>(
      xb, wqkv, qb, bq, bk, 2048, E_, 1.f,
      0, 0, 0, E_, E_, 1024, 8, 32);

  // 3) v-projection, transposed: vt[b] = Wv x[b]^T  (M=1024, N=2048, z=4)
  gemm256<128, 1, 0><<<256, 512, 0, stream>>>(
      wqkv + 2 * (size_t)E_ * E_, xb, vt, bv, nullptr, 2048, E_, 1.f,
      0, (long)S_ * E_, (long)1024 * LDP, E_, E_, LDP, 16, 4);

  // 4) expS = exp(q k^T / 32)  (256 blocks)
  gemm256<256, 2, 0><<<256, 512, 0, stream>>>(
      qb, qb + 8388608, Pm, nullptr, nullptr, 2048, E_, 0.03125f,
      (long)S_ * 1024, (long)S_ * 1024, (long)2048 * LDP, 1024, 1024, LDP, 8, 8);

  // 5) row inverse sums
  row_invsum<<<B_ * S_ / 4, 256, 0, stream>>>(Pm, invL);

  // 6) out += (expS[:, ks*1024:+1024] @ V[ks]) * invL  — split-K=2, BN=256,
  //    256 blocks (128 per half), atomic fp32 accumulate
  gemm256<256, 4, 1><<<256, 512, 0, stream>>>(
      Pm, vt, out, invL, nullptr, E_, 1024, 1.f,
      (long)2048 * LDP, (long)1024 * LDP, (long)S_ * E_, LDP, LDP, 1024, 4, 8);
}

// Round 10
// 157.807 us; speedup vs baseline: 1.2709x; 1.2709x over previous
//
#include <hip/hip_runtime.h>
#include <stdint.h>

#define B_   4
#define S_   2048
#define E_   1024
#define MQKV (B_ * S_)
#define LDP  2112   // padded row stride (u16) for Pm and vt

typedef __bf16 bf16x8 __attribute__((ext_vector_type(8)));
typedef float f32x4 __attribute__((ext_vector_type(4)));
typedef unsigned short u16;
typedef unsigned int u32;

__device__ __forceinline__ u16 f2bf(float x) {
  union { float f; u32 u; } c; c.f = x;
  u32 r = (c.u + 0x7FFFu + ((c.u >> 16) & 1u)) >> 16;
  return (u16)r;
}
__device__ __forceinline__ float bf2f(u16 h) {
  union { u32 u; float f; } c; c.u = ((u32)h) << 16;
  return c.f;
}

__global__ __launch_bounds__(256) void cvt_f32_bf16(const float* __restrict__ src,
                                                    u16* __restrict__ dst, int n4) {
  int i = blockIdx.x * blockDim.x + threadIdx.x;
  int st = gridDim.x * blockDim.x;
  for (; i < n4; i += st) {
    float4 f = reinterpret_cast<const float4*>(src)[i];
    ushort4 o;
    o.x = f2bf(f.x); o.y = f2bf(f.y); o.z = f2bf(f.z); o.w = f2bf(f.w);
    reinterpret_cast<ushort4*>(dst)[i] = o;
  }
}

__global__ __launch_bounds__(256) void cvt_w3(const float* __restrict__ wq,
                                              const float* __restrict__ wk,
                                              const float* __restrict__ wv,
                                              u16* __restrict__ dst) {
  const int per = E_ * E_ / 4;
  int i = blockIdx.x * blockDim.x + threadIdx.x;
  const int sel = i / per;
  const int r = i - sel * per;
  const float* src = sel == 0 ? wq : (sel == 1 ? wk : wv);
  float4 f = reinterpret_cast<const float4*>(src)[r];
  ushort4 o;
  o.x = f2bf(f.x); o.y = f2bf(f.y); o.z = f2bf(f.z); o.w = f2bf(f.w);
  reinterpret_cast<ushort4*>(dst)[i] = o;
}

#define GLOAD_LDS16(g, l)                                                      \
  __builtin_amdgcn_global_load_lds(                                            \
      (const __attribute__((address_space(1))) u32*)(g),                       \
      (__attribute__((address_space(3))) u32*)(l), 16, 0, 0)

// ============================================================================
// 256-row-tile GEMM body (ring), 8 waves (2M x 4N), BK=32, 4-slot LDS ring,
// counted vmcnt, 2-way-free XOR swizzle (chunk ^= (row>>1)&3), setprio,
// XCD swizzle. C = A(M x K, ldA) * Bt(N x K, ldB)^T, bf16 in, f32 acc.
// EPI 0: qk-projection: +bias, scatter col<1024 -> q, else -> k
// EPI 1: v-projection-transposed: +b0[row], bf16, ldC-strided (z-batched)
// EPI 2: exp(v*scale), bf16, ldC-strided
// EPI 3: v * b0[z*2048+row] (invL), fp32, ldC-strided (final out)
// ============================================================================
template <int BN, int EPI>
__device__ __forceinline__ void gemm_body(
    const u16* __restrict__ A, const u16* __restrict__ Bt, void* __restrict__ Cv,
    const float* __restrict__ b0, const float* __restrict__ b1,
    int N, int K, float scale,
    long sA, long sB, long sC, long ldA, long ldB, long ldC, int gx, int gy) {
  constexpr int BM = 256;
  constexpr int NR = BN / 64;
  constexpr int L  = 2 + BN / 128;
  constexpr int BSLOT = BN * 32;

  __shared__ alignas(16) u16 lds[4 * BM * 32 + 4 * BSLOT];
  u16* lA = lds;
  u16* lB = lds + 4 * BM * 32;

  const int t = threadIdx.x;
  const int wv = t >> 6;
  const int ln = t & 63;
  const int wm = wv >> 2;
  const int wn = wv & 3;

  const int nwg = gridDim.x;
  int id = blockIdx.x;
  id = (id & 7) * (nwg >> 3) + (id >> 3);
  const int pz = gx * gy;
  const int z = id / pz;
  const int r2 = id - z * pz;
  const int by = r2 / gx;
  const int bx = r2 - by * gx;
  const int bm = by * BM;
  const int bn = bx * BN;

  A += (size_t)z * sA;
  Bt += (size_t)z * sB;

  const int srow = t >> 2;
  const int g0 = (t & 3) ^ ((srow >> 1) & 3);       // 2-way-free swizzle
  const u16* gA0 = A + (size_t)(bm + srow) * ldA + g0 * 8;
  const u16* gA1 = gA0 + (size_t)128 * ldA;
  const u16* gB0 = Bt + (size_t)(bn + srow) * ldB + g0 * 8;
  const u16* gB1 = gB0 + (size_t)128 * ldB;

  auto STAGE = [&](int u) {
    const int s = u & 3;
    const int ko = u * 32;
    GLOAD_LDS16(gA0 + ko, lA + s * 8192 + wv * 512);
    GLOAD_LDS16(gA1 + ko, lA + s * 8192 + 4096 + wv * 512);
    GLOAD_LDS16(gB0 + ko, lB + s * BSLOT + wv * 512);
    if constexpr (BN == 256) GLOAD_LDS16(gB1 + ko, lB + s * BSLOT + 4096 + wv * 512);
  };

  const int lrow = ln & 15;
  const int g = ln >> 4;
  const int aR = wm * 128 + lrow;
  const int aOff = aR * 32 + (g ^ ((aR >> 1) & 3)) * 8;
  const int bR = wn * (BN / 4) + lrow;
  const int bOff = bR * 32 + (g ^ ((bR >> 1) & 3)) * 8;

  f32x4 acc[8][NR] = {};
  const int T = K >> 5;

  bf16x8 afA[8], afB[8], bgA[NR], bgB[NR];

#define RD_A(DST, TILE) do { const u16* _p = lA + ((TILE) & 3) * 8192 + aOff;  \
  _Pragma("unroll") for (int _i = 0; _i < 8; ++_i)                             \
    DST[_i] = *reinterpret_cast<const bf16x8*>(_p + _i * 512); } while (0)
#define RD_B(DST, TILE) do { const u16* _p = lB + ((TILE) & 3) * BSLOT + bOff; \
  _Pragma("unroll") for (int _j = 0; _j < NR; ++_j)                            \
    DST[_j] = *reinterpret_cast<const bf16x8*>(_p + _j * 512); } while (0)
#define DO_MFMA(AF, BG) do { __builtin_amdgcn_s_setprio(1);                    \
  _Pragma("unroll") for (int _i = 0; _i < 8; ++_i)                             \
  _Pragma("unroll") for (int _j = 0; _j < NR; ++_j)                            \
    acc[_i][_j] = __builtin_amdgcn_mfma_f32_16x16x32_bf16(AF[_i], BG[_j],      \
                                                          acc[_i][_j], 0, 0, 0);\
  __builtin_amdgcn_s_setprio(0); } while (0)
#define VM_GATE(COND) do {                                                     \
  if (COND) { asm volatile("s_waitcnt vmcnt(%0)" :: "n"(L) : "memory"); }      \
  else { asm volatile("s_waitcnt vmcnt(0)" ::: "memory"); }                    \
  __builtin_amdgcn_s_barrier(); asm volatile("" ::: "memory"); } while (0)

  STAGE(0); STAGE(1); STAGE(2);
  asm volatile("s_waitcnt vmcnt(%0)" :: "n"(L) : "memory");
  __builtin_amdgcn_s_barrier();
  asm volatile("" ::: "memory");

  if constexpr (NR == 2) { RD_A(afA, 0); RD_B(bgA, 0); }
  else                   { RD_B(bgA, 0); }

  for (int tt = 0; tt < T; tt += 2) {
    if (tt + 3 < T) STAGE(tt + 3);
    if constexpr (NR == 2) { RD_A(afB, tt + 1); RD_B(bgB, tt + 1); DO_MFMA(afA, bgA); }
    else                   { RD_A(afA, tt); RD_B(bgB, tt + 1);     DO_MFMA(afA, bgA); }
    VM_GATE(tt + 3 < T);

    if (tt + 4 < T) STAGE(tt + 4);
    if constexpr (NR == 2) {
      if (tt + 2 < T) { RD_A(afA, tt + 2); RD_B(bgA, tt + 2); }
      DO_MFMA(afB, bgB);
    } else {
      RD_A(afA, tt + 1);
      if (tt + 2 < T) RD_B(bgA, tt + 2);
      DO_MFMA(afA, bgB);
    }
    VM_GATE(tt + 4 < T);
  }
#undef RD_A
#undef RD_B
#undef DO_MFMA
#undef VM_GATE

  const int r0 = (ln >> 4) * 4;
  const int c0 = ln & 15;
#pragma unroll
  for (int i = 0; i < 8; ++i) {
#pragma unroll
    for (int j = 0; j < NR; ++j) {
      const int col = bn + wn * (BN / 4) + j * 16 + c0;
#pragma unroll
      for (int ii = 0; ii < 4; ++ii) {
        const int row = bm + wm * 128 + i * 16 + r0 + ii;
        float v = acc[i][j][ii];
        if constexpr (EPI == 0) {
          const int sel = col >> 10;
          const int cc = col & 1023;
          const float bb = sel == 0 ? b0[cc] : b1[cc];
          ((u16*)Cv)[(size_t)sel * 8388608 + (size_t)row * 1024 + cc] = f2bf(v + bb);
        } else if constexpr (EPI == 1) {
          ((u16*)Cv)[(size_t)z * sC + (size_t)row * ldC + col] = f2bf(v + b0[row]);
        } else if constexpr (EPI == 2) {
          ((u16*)Cv)[(size_t)z * sC + (size_t)row * ldC + col] = f2bf(__expf(v * scale));
        } else {
          ((float*)Cv)[(size_t)z * sC + (size_t)row * ldC + col] = v * b0[z * 2048 + row];
        }
      }
    }
  }
}

// ---- distinctly-named wrappers (per-stage rocprof attribution) ----
__global__ __launch_bounds__(512, 2) void qkproj_k(
    const u16* __restrict__ A, const u16* __restrict__ Bt, void* __restrict__ Cv,
    const float* __restrict__ b0, const float* __restrict__ b1,
    int N, int K, float scale, long sA, long sB, long sC,
    long ldA, long ldB, long ldC, int gx, int gy) {
  gemm_body<256, 0>(A, Bt, Cv, b0, b1, N, K, scale, sA, sB, sC, ldA, ldB, ldC, gx, gy);
}
__global__ __launch_bounds__(512, 2) void vproj_k(
    const u16* __restrict__ A, const u16* __restrict__ Bt, void* __restrict__ Cv,
    const float* __restrict__ b0, const float* __restrict__ b1,
    int N, int K, float scale, long sA, long sB, long sC,
    long ldA, long ldB, long ldC, int gx, int gy) {
  gemm_body<128, 1>(A, Bt, Cv, b0, b1, N, K, scale, sA, sB, sC, ldA, ldB, ldC, gx, gy);
}
__global__ __launch_bounds__(512, 2) void qkt_k(
    const u16* __restrict__ A, const u16* __restrict__ Bt, void* __restrict__ Cv,
    const float* __restrict__ b0, const float* __restrict__ b1,
    int N, int K, float scale, long sA, long sB, long sC,
    long ldA, long ldB, long ldC, int gx, int gy) {
  gemm_body<256, 2>(A, Bt, Cv, b0, b1, N, K, scale, sA, sB, sC, ldA, ldB, ldC, gx, gy);
}
__global__ __launch_bounds__(512, 2) void pv_k(
    const u16* __restrict__ A, const u16* __restrict__ Bt, void* __restrict__ Cv,
    const float* __restrict__ b0, const float* __restrict__ b1,
    int N, int K, float scale, long sA, long sB, long sC,
    long ldA, long ldB, long ldC, int gx, int gy) {
  gemm_body<128, 3>(A, Bt, Cv, b0, b1, N, K, scale, sA, sB, sC, ldA, ldB, ldC, gx, gy);
}

// invL[row] = 1 / sum(expS[row][:2048]) ; one wave per row; Pm rows LDP-strided
__global__ __launch_bounds__(256) void row_invsum(const u16* __restrict__ P,
                                                  float* __restrict__ invL) {
  const int row = blockIdx.x * 4 + (threadIdx.x >> 6);
  const int ln = threadIdx.x & 63;
  const u16* p = P + (size_t)row * LDP + ln * 32;
  float s = 0.f;
#pragma unroll
  for (int q = 0; q < 4; ++q) {
    uint4 r = reinterpret_cast<const uint4*>(p)[q];
    u32 w[4] = {r.x, r.y, r.z, r.w};
#pragma unroll
    for (int k = 0; k < 4; ++k) {
      s += bf2f((u16)(w[k] & 0xffffu));
      s += bf2f((u16)(w[k] >> 16));
    }
  }
  for (int o = 1; o < 64; o <<= 1) s += __shfl_xor(s, o);
  if (ln == 0) invL[row] = 1.0f / s;
}

extern "C" void kernel_launch(void* const* d_in, const int* in_sizes, int n_in,
                              void* d_out, int out_size, void* d_ws, size_t ws_size,
                              hipStream_t stream) {
  const float* x = (const float*)d_in[0];
  const float* Wq = (const float*)d_in[1];
  const float* bq = (const float*)d_in[2];
  const float* Wk = (const float*)d_in[3];
  const float* bk = (const float*)d_in[4];
  const float* Wv = (const float*)d_in[5];
  const float* bv = (const float*)d_in[6];
  float* out = (float*)d_out;

  const size_t xE = 8388608, wE = 3145728, qE = 8388608;
  const size_t vtE = (size_t)4 * 1024 * LDP;
  const size_t PmE = (size_t)4 * 2048 * LDP;
  const size_t need = (xE + wE + 2 * qE + vtE + PmE) * 2 + (size_t)MQKV * 4;
  if (ws_size < need) {
    hipMemsetAsync(d_out, 0, (size_t)out_size * sizeof(float), stream);
    return;
  }
  u16* xb = (u16*)d_ws;
  u16* wqkv = xb + xE;
  u16* qb = wqkv + wE;            // k at qb + 8388608 (EPI0 hardcodes the offset)
  u16* vt = qb + 2 * qE;
  u16* Pm = vt + vtE;
  float* invL = (float*)(Pm + PmE);

  // 1) fp32 -> bf16
  cvt_f32_bf16<<<2048, 256, 0, stream>>>(x, xb, MQKV * E_ / 4);
  cvt_w3<<<3 * E_ * E_ / 4 / 256, 256, 0, stream>>>(Wq, Wk, Wv, wqkv);

  // 2) qk-projection: [8192,1024] x [2048,1024]^T -> q | k (256 blocks)
  qkproj_k<<<256, 512, 0, stream>>>(
      xb, wqkv, qb, bq, bk, 2048, E_, 1.f,
      0, 0, 0, E_, E_, 1024, 8, 32);

  // 3) v-projection, transposed: vt[b] = Wv x[b]^T  (M=1024, N=2048, z=4)
  vproj_k<<<256, 512, 0, stream>>>(
      wqkv + 2 * (size_t)E_ * E_, xb, vt, bv, nullptr, 2048, E_, 1.f,
      0, (long)S_ * E_, (long)1024 * LDP, E_, E_, LDP, 16, 4);

  // 4) expS = exp(q k^T / 32)  (256 blocks)
  qkt_k<<<256, 512, 0, stream>>>(
      qb, qb + 8388608, Pm, nullptr, nullptr, 2048, E_, 0.03125f,
      (long)S_ * 1024, (long)S_ * 1024, (long)2048 * LDP, 1024, 1024, LDP, 8, 8);

  // 5) row inverse sums
  row_invsum<<<B_ * S_ / 4, 256, 0, stream>>>(Pm, invL);

  // 6) out = (expS @ V) * invL  (A, B both LDP-strided; out natural ld 1024)
  pv_k<<<256, 512, 0, stream>>>(
      Pm, vt, out, invL, nullptr, E_, S_, 1.f,
      (long)2048 * LDP, (long)1024 * LDP, (long)S_ * E_, LDP, LDP, 1024, 8, 8);
}